// Round 5
// baseline (263.177 us; speedup 1.0000x reference)
//
#include <hip/hip_runtime.h>
#include <stdint.h>

#define D_MODEL 1024
#define N_HEADS 16
#define HEAD_DIM 64
#define BATCH 4
#define SEQ 2048
#define ROWS (BATCH * SEQ)   /* 8192 */
#define K3 (3 * D_MODEL)     /* 3072 */
#define NQT (SEQ / 64)       /* 32 q-tiles of 64 */
#define SCALE_Q 0.1803368867f /* 0.125 * log2(e): QK scores land in exp2 domain */

typedef unsigned short u16;
typedef unsigned int u32;
typedef __attribute__((ext_vector_type(8))) short short8;
typedef __attribute__((ext_vector_type(4))) float floatx4;

typedef const __attribute__((address_space(1))) u32* gptr_t;
typedef __attribute__((address_space(3))) u32* lptr_t;

// Packed f32x2 -> bf16x2 (RNE) in ONE instruction (m240-verified mnemonic).
__device__ __forceinline__ unsigned cvt_pk(float lo, float hi) {
    unsigned r;
    asm("v_cvt_pk_bf16_f32 %0, %1, %2" : "=v"(r) : "v"(lo), "v"(hi));
    return r;
}

// ------------------------------------------------------------ fused prep
// One kernel replaces conv_f2b4 + 2x transpose_f2b_t (saves 2 launch gaps).
// Blocks [0,8192): x fp32 -> bf16 (vectorized). [8192,8960): w_qkv transpose.
// [8960,9216): w_proj transpose. Whole blocks take one path (no divergence).
__global__ __launch_bounds__(256) void prep_fused(const float* __restrict__ x,
                                                  u16* __restrict__ xb,
                                                  const float* __restrict__ w_qkv,
                                                  u16* __restrict__ wt_qkv,
                                                  const float* __restrict__ w_proj,
                                                  u16* __restrict__ wt_proj) {
    __shared__ u16 tile[64][65];
    const int bid = blockIdx.x;
    if (bid < 8192) {
        const int i = bid * 256 + threadIdx.x;
        float4 v = ((const float4*)x)[i];
        uint2 p;
        p.x = cvt_pk(v.x, v.y);
        p.y = cvt_pk(v.z, v.w);
        ((uint2*)xb)[i] = p;
        return;
    }
    const float* w;
    u16* wt;
    int C, bx, by;
    if (bid < 8192 + 768) {
        const int r = bid - 8192;
        w = w_qkv; wt = wt_qkv; C = K3;
        bx = r % 48; by = r / 48;
    } else {
        const int r = bid - 8960;
        w = w_proj; wt = wt_proj; C = D_MODEL;
        bx = r & 15; by = r >> 4;
    }
    const int R = D_MODEL;
    const int tx = threadIdx.x & 63;
    const int ty = threadIdx.x >> 6;
    const int r0 = by * 64, c0 = bx * 64;
    #pragma unroll
    for (int i = 0; i < 16; i += 2) {
        const float a = w[(size_t)(r0 + i * 4 + ty) * C + c0 + tx];
        const float b = w[(size_t)(r0 + (i + 1) * 4 + ty) * C + c0 + tx];
        const unsigned p = cvt_pk(a, b);
        tile[i * 4 + ty][tx] = (u16)p;
        tile[(i + 1) * 4 + ty][tx] = (u16)(p >> 16);
    }
    __syncthreads();
    #pragma unroll
    for (int i = 0; i < 16; ++i) {
        const int c = i * 4 + ty;
        wt[(size_t)(c0 + c) * R + r0 + tx] = tile[tx][c];
    }
}

// ---------------------------------------------------------------- GEMM core
// m97-pattern: 128x128 tile, BK=64, global_load_lds width=16 into unpadded
// [128][64] LDS with XOR swizzle; frag ds_read_b128 conflict-free.
// SM pool is reused by the v-transpose epilogue in gemm_qkv after the final
// barrier. NXB = gridDim.x (compile-time) so XCD-swizzle div/mod folds.
#define GEMM_CORE_GLD(KDIM, NXB)                                               \
    __shared__ u16 SM[2][128][64];                                             \
    u16 (*As)[64] = SM[0];                                                     \
    u16 (*Bs)[64] = SM[1];                                                     \
    const int tid  = threadIdx.x;                                              \
    const int wave = tid >> 6, lane = tid & 63;                                \
    const int quad = lane >> 4, l15 = lane & 15;                               \
    const int wr = wave >> 1, wc = wave & 1;                                   \
    const int bid = (int)(blockIdx.y * gridDim.x + blockIdx.x);                \
    const int nwg = (int)(gridDim.x * gridDim.y);                              \
    const int swz = (bid & 7) * (nwg >> 3) + (bid >> 3);   /* XCD swizzle */   \
    const int m0 = (swz / (NXB)) * 128, n0 = (swz % (NXB)) * 128;              \
    const int lrow8 = lane >> 3;                                               \
    const int csw = 8 * ((lane & 7) ^ lrow8);      /* load-side swizzle */     \
    const int swA = (l15 & 7) * 8;                 /* read-side xor     */     \
    floatx4 acc[4][4] = {};                                                    \
    for (int k0 = 0; k0 < (KDIM); k0 += 64) {                                  \
        _Pragma("unroll")                                                      \
        for (int i = 0; i < 4; ++i) {                                          \
            const int rb = i * 32 + wave * 8;                                  \
            const int r  = rb + lrow8;                                         \
            __builtin_amdgcn_global_load_lds(                                  \
                (gptr_t)(A + (size_t)(m0 + r) * (KDIM) + k0 + csw),            \
                (lptr_t)(&As[rb][0]), 16, 0, 0);                               \
            __builtin_amdgcn_global_load_lds(                                  \
                (gptr_t)(Bt + (size_t)(n0 + r) * (KDIM) + k0 + csw),           \
                (lptr_t)(&Bs[rb][0]), 16, 0, 0);                               \
        }                                                                      \
        __syncthreads();                                                       \
        _Pragma("unroll")                                                      \
        for (int ks = 0; ks < 2; ++ks) {                                       \
            const int kk = ks * 32 + quad * 8;                                 \
            short8 af[4], bf[4];                                               \
            _Pragma("unroll")                                                  \
            for (int t = 0; t < 4; ++t) {                                      \
                af[t] = *(const short8*)&As[wr * 64 + t * 16 + l15][kk ^ swA]; \
                bf[t] = *(const short8*)&Bs[wc * 64 + t * 16 + l15][kk ^ swA]; \
            }                                                                  \
            _Pragma("unroll")                                                  \
            for (int i = 0; i < 4; ++i)                                        \
                _Pragma("unroll")                                              \
                for (int j = 0; j < 4; ++j)                                    \
                    acc[i][j] = __builtin_amdgcn_mfma_f32_16x16x32_bf16(       \
                        af[i], bf[j], acc[i][j], 0, 0, 0);                     \
        }                                                                      \
        __syncthreads();                                                       \
    }

// GEMM1: xb @ wqkv -> q (pre-scaled) and k as [BH][T][64]; v written DIRECTLY
// TRANSPOSED as vt[BH][64][T] via an LDS-staged epilogue (replaces the
// standalone transpose_v2 kernel: -1 dispatch, -32MB HBM traffic).
__global__ __launch_bounds__(256) void gemm_qkv(const u16* __restrict__ A,
                                                const u16* __restrict__ Bt,
                                                u16* __restrict__ qo,
                                                u16* __restrict__ ko,
                                                u16* __restrict__ vt) {
    GEMM_CORE_GLD(D_MODEL, 24)
    const int which = n0 >> 10;                 // block-uniform
    if (which == 2) {
        // ---- v-blocks: acc -> LDS (transposed, XOR-swizzled 16B chunks)
        // wc=0 waves own head h0, wc=1 waves own h0+1; each head's region is
        // SM[wc] viewed as [64 d][128 t] (16KB). Swizzle byte^=(d&7)<<5 keeps
        // writes 2-way and reads 4-way max.
        char* Tv = (char*)&SM[wc][0][0];
        #pragma unroll
        for (int i = 0; i < 4; ++i) {
            const int tb = wr * 64 + i * 16 + quad * 4;
            #pragma unroll
            for (int j = 0; j < 4; ++j) {
                const int d = j * 16 + l15;
                const unsigned xo = (unsigned)((d & 7) << 5);
                char* base = Tv + d * 256;
                *(u32*)(base + (((tb + 0) * 2) ^ xo)) =
                    cvt_pk(acc[i][j][0], acc[i][j][1]);
                *(u32*)(base + (((tb + 2) * 2) ^ xo)) =
                    cvt_pk(acc[i][j][2], acc[i][j][3]);
            }
        }
        __syncthreads();
        // ---- coalesced 16B stores: lane pair (d, t-half) -> 128B run
        const int idx = wr * 64 + lane;       // 0..127 within wc-group
        const int d = idx >> 1, tb2 = (idx & 1) * 64;
        const int b_ = m0 >> 11, t0 = m0 & 2047;
        const int h = ((n0 - 2048) >> 6) + wc;
        u16* dst = vt + ((size_t)(b_ * N_HEADS + h) * HEAD_DIM + d) * SEQ + t0 + tb2;
        const char* src = (const char*)&SM[wc][0][0] + d * 256;
        const unsigned xo = (unsigned)((d & 7) << 5);
        #pragma unroll
        for (int c8 = 0; c8 < 8; ++c8) {
            const uint4 vv = *(const uint4*)(src + (((tb2 + c8 * 8) * 2) ^ xo));
            *(uint4*)(dst + c8 * 8) = vv;
        }
        return;
    }
    u16* dst = which == 0 ? qo : ko;
    const float scl = which == 0 ? SCALE_Q : 1.f;
    #pragma unroll
    for (int i = 0; i < 4; ++i)
        #pragma unroll
        for (int j = 0; j < 4; ++j) {
            const int col = n0 + wc * 64 + j * 16 + l15;
            const int rb  = m0 + wr * 64 + i * 16 + quad * 4;
            const int cc  = col & 1023;
            const int h = cc >> 6, d = cc & 63;
            #pragma unroll
            for (int rr = 0; rr < 4; rr += 2) {
                const unsigned pw = cvt_pk(acc[i][j][rr] * scl,
                                           acc[i][j][rr + 1] * scl);
                int row = rb + rr;
                int b_ = row >> 11, t_ = row & 2047;
                dst[(((size_t)(b_ * N_HEADS + h)) * SEQ + t_) * HEAD_DIM + d] =
                    (u16)pw;
                row = rb + rr + 1;
                b_ = row >> 11; t_ = row & 2047;
                dst[(((size_t)(b_ * N_HEADS + h)) * SEQ + t_) * HEAD_DIM + d] =
                    (u16)(pw >> 16);
            }
        }
}

// GEMM2: attn_out[8192][1024] @ wproj + bias -> d_out fp32
__global__ __launch_bounds__(256) void gemm_proj(const u16* __restrict__ A,
                                                 const u16* __restrict__ Bt,
                                                 const float* __restrict__ bias,
                                                 float* __restrict__ out) {
    GEMM_CORE_GLD(D_MODEL, 8)
    #pragma unroll
    for (int i = 0; i < 4; ++i)
        #pragma unroll
        for (int j = 0; j < 4; ++j) {
            const int col = n0 + wc * 64 + j * 16 + l15;
            const int rb  = m0 + wr * 64 + i * 16 + quad * 4;
            const float bv = bias[col];
            #pragma unroll
            for (int rr = 0; rr < 4; ++rr) {
                const int row = rb + rr;
                out[(size_t)row * D_MODEL + col] = acc[i][j][rr] + bv;
            }
        }
}

// ------------------------------------------------------- MFMA flash attention
// REVERTED to the Round-3 structure (measured 74.6us): K=32 MFMAs + Plds
// round-trip. (Round-4's K=16 in-register PV doubled MFMA issue count and
// 4x'd bank conflicts -> net regression.) Only addition: T5 s_setprio around
// the MFMA clusters (m191: +4-7% on attn, within-probe verified).
__global__ __launch_bounds__(256, 4) void attn_mfma(const u16* __restrict__ q,
                                                    const u16* __restrict__ k,
                                                    const u16* __restrict__ vt,
                                                    u16* __restrict__ o) {
    __shared__ u16 Ks[2][64][64];
    __shared__ u16 Vs[2][64][64];
    __shared__ u16 Plds[4][16][64];
    const int tid = threadIdx.x;
    const int w = tid >> 6, lane = tid & 63;
    const int quad = lane >> 4, l15 = lane & 15;
    const int bid = (int)(blockIdx.y * 16 + blockIdx.x);
    const int swzb = (bid & 7) * 128 + (bid >> 3);
    const int bh = swzb >> 4;
    const int qx = swzb & 15;
    const int b = bh >> 4, h = bh & 15;
    const u16* kb  = k  + (size_t)bh * SEQ * HEAD_DIM;
    const u16* vtb = vt + (size_t)bh * HEAD_DIM * SEQ;
    const int lrow8 = lane >> 3;                   // 0..7
    const int csw = 8 * ((lane & 7) ^ lrow8);      // load-side swizzle
    const int swA = (l15 & 7) * 8;                 // read-side xor
    const int r0 = w * 16 + lrow8;                 // staging row
    const short8 ones = {0x3F80, 0x3F80, 0x3F80, 0x3F80,
                         0x3F80, 0x3F80, 0x3F80, 0x3F80}; // bf16 1.0 x8

    #pragma unroll 1
    for (int seg = 0; seg < 2; ++seg) {
        const int qt = seg ? qx : (NQT - 1 - qx);
        const int qrow = qt * 64 + w * 16 + l15;
        const u16* qp = q + ((size_t)bh * SEQ + qrow) * HEAD_DIM + quad * 8;
        const short8 bq0 = *(const short8*)(qp);
        const short8 bq1 = *(const short8*)(qp + 32);

        floatx4 O[4] = {};
        floatx4 Lacc = {};

        __syncthreads();   // prior segment's buffer reads complete
        // stage chunk 0 -> buffer 0
        __builtin_amdgcn_global_load_lds(
            (gptr_t)(kb + (size_t)(r0) * HEAD_DIM + csw),
            (lptr_t)(&Ks[0][w * 16][0]), 16, 0, 0);
        __builtin_amdgcn_global_load_lds(
            (gptr_t)(kb + (size_t)(r0 + 8) * HEAD_DIM + csw),
            (lptr_t)(&Ks[0][w * 16 + 8][0]), 16, 0, 0);
        __builtin_amdgcn_global_load_lds(
            (gptr_t)(vtb + (size_t)(r0) * SEQ + csw),
            (lptr_t)(&Vs[0][w * 16][0]), 16, 0, 0);
        __builtin_amdgcn_global_load_lds(
            (gptr_t)(vtb + (size_t)(r0 + 8) * SEQ + csw),
            (lptr_t)(&Vs[0][w * 16 + 8][0]), 16, 0, 0);

        for (int c = 0; c <= qt; ++c) {
            const int cb = c & 1;
            __syncthreads();   // staging(c) drained everywhere; buf[(c+1)&1] free
            if (c < qt) {
                const int nb = cb ^ 1;
                __builtin_amdgcn_global_load_lds(
                    (gptr_t)(kb + (size_t)((c + 1) * 64 + r0) * HEAD_DIM + csw),
                    (lptr_t)(&Ks[nb][w * 16][0]), 16, 0, 0);
                __builtin_amdgcn_global_load_lds(
                    (gptr_t)(kb + (size_t)((c + 1) * 64 + r0 + 8) * HEAD_DIM + csw),
                    (lptr_t)(&Ks[nb][w * 16 + 8][0]), 16, 0, 0);
                __builtin_amdgcn_global_load_lds(
                    (gptr_t)(vtb + (size_t)(r0) * SEQ + (c + 1) * 64 + csw),
                    (lptr_t)(&Vs[nb][w * 16][0]), 16, 0, 0);
                __builtin_amdgcn_global_load_lds(
                    (gptr_t)(vtb + (size_t)(r0 + 8) * SEQ + (c + 1) * 64 + csw),
                    (lptr_t)(&Vs[nb][w * 16 + 8][0]), 16, 0, 0);
            }
            // ---- QK^T from LDS buf cb
            floatx4 s[4];
            #pragma unroll
            for (int kt = 0; kt < 4; ++kt) {
                short8 ak0 = *(const short8*)&Ks[cb][kt * 16 + l15][(quad * 8) ^ swA];
                short8 ak1 = *(const short8*)&Ks[cb][kt * 16 + l15][(32 + quad * 8) ^ swA];
                floatx4 z = {};
                __builtin_amdgcn_s_setprio(1);
                z = __builtin_amdgcn_mfma_f32_16x16x32_bf16(ak0, bq0, z, 0, 0, 0);
                z = __builtin_amdgcn_mfma_f32_16x16x32_bf16(ak1, bq1, z, 0, 0, 0);
                __builtin_amdgcn_s_setprio(0);
                s[kt] = z;
            }
            // ---- exp2 (m=0) + diagonal mask
            float e[4][4];
            #pragma unroll
            for (int kt = 0; kt < 4; ++kt)
                #pragma unroll
                for (int r = 0; r < 4; ++r)
                    e[kt][r] = exp2f(s[kt][r]);
            if (c == qt) {
                #pragma unroll
                for (int kt = 0; kt < 4; ++kt)
                    #pragma unroll
                    for (int r = 0; r < 4; ++r)
                        if (kt * 16 + quad * 4 + r > w * 16 + l15) e[kt][r] = 0.f;
            }
            // ---- P->LDS (packed cvt_pk, swizzled cols)
            #pragma unroll
            for (int kt = 0; kt < 4; ++kt) {
                uint2 pkv;
                pkv.x = cvt_pk(e[kt][0], e[kt][1]);
                pkv.y = cvt_pk(e[kt][2], e[kt][3]);
                *(uint2*)&Plds[w][l15][(kt * 16 + quad * 4) ^ swA] = pkv;
            }
            // ---- PV from LDS: O^T += Vs . P^T ; l via ones-row MFMA over P
            short8 pb0 = *(const short8*)&Plds[w][l15][(quad * 8) ^ swA];
            short8 pb1 = *(const short8*)&Plds[w][l15][(32 + quad * 8) ^ swA];
            __builtin_amdgcn_s_setprio(1);
            #pragma unroll
            for (int dt = 0; dt < 4; ++dt) {
                short8 av0 = *(const short8*)&Vs[cb][dt * 16 + l15][(quad * 8) ^ swA];
                short8 av1 = *(const short8*)&Vs[cb][dt * 16 + l15][(32 + quad * 8) ^ swA];
                O[dt] = __builtin_amdgcn_mfma_f32_16x16x32_bf16(av0, pb0, O[dt], 0, 0, 0);
                O[dt] = __builtin_amdgcn_mfma_f32_16x16x32_bf16(av1, pb1, O[dt], 0, 0, 0);
            }
            Lacc = __builtin_amdgcn_mfma_f32_16x16x32_bf16(ones, pb0, Lacc, 0, 0, 0);
            Lacc = __builtin_amdgcn_mfma_f32_16x16x32_bf16(ones, pb1, Lacc, 0, 0, 0);
            __builtin_amdgcn_s_setprio(0);
        }
        // ---- epilogue: l is already the full-row sum in every Lacc reg
        const float inv = 1.f / Lacc[0];
        u16* op = o + ((size_t)(b * SEQ + qrow)) * D_MODEL + h * 64 + quad * 4;
        #pragma unroll
        for (int dt = 0; dt < 4; ++dt) {
            uint2 pkv;
            pkv.x = cvt_pk(O[dt][0] * inv, O[dt][1] * inv);
            pkv.y = cvt_pk(O[dt][2] * inv, O[dt][3] * inv);
            *(uint2*)(op + dt * 16) = pkv;
        }
    }
}

// ---------------------------------------------------------------- launch
extern "C" void kernel_launch(void* const* d_in, const int* in_sizes, int n_in,
                              void* d_out, int out_size, void* d_ws, size_t ws_size,
                              hipStream_t stream) {
    const float* x      = (const float*)d_in[0];
    const float* w_qkv  = (const float*)d_in[1];
    const float* w_proj = (const float*)d_in[2];
    const float* b_proj = (const float*)d_in[3];
    float* out = (float*)d_out;

    u16* xb      = (u16*)d_ws;                                 // [8192][1024]
    u16* wt_qkv  = xb + (size_t)ROWS * D_MODEL;                // [3072][1024]
    u16* wt_proj = wt_qkv + (size_t)D_MODEL * K3;              // [1024][1024]
    u16* qws     = wt_proj + (size_t)D_MODEL * D_MODEL;        // [BH][T][64] (pre-scaled)
    u16* kws     = qws + (size_t)ROWS * D_MODEL;               // [BH][T][64]
    u16* vtws    = kws + (size_t)ROWS * D_MODEL;               // [BH][64][T]
    u16* aout    = vtws + (size_t)ROWS * D_MODEL;              // [8192][1024]

    // 4 kernels (was 7): prep -> gemm_qkv(+v-transpose) -> attn -> gemm_proj
    prep_fused<<<8192 + 768 + 256, 256, 0, stream>>>(x, xb, w_qkv, wt_qkv,
                                                     w_proj, wt_proj);

    gemm_qkv<<<dim3(K3 / 128, ROWS / 128), 256, 0, stream>>>(xb, wt_qkv, qws, kws, vtws);

    attn_mfma<<<dim3(NQT / 2, BATCH * N_HEADS), 256, 0, stream>>>(qws, kws, vtws, aout);

    gemm_proj<<<dim3(D_MODEL / 128, ROWS / 128), 256, 0, stream>>>(aout, wt_proj, b_proj, out);
}

// Round 6
// 251.845 us; speedup vs baseline: 1.0450x; 1.0450x over previous
//
#include <hip/hip_runtime.h>
#include <stdint.h>

#define D_MODEL 1024
#define N_HEADS 16
#define HEAD_DIM 64
#define BATCH 4
#define SEQ 2048
#define ROWS (BATCH * SEQ)   /* 8192 */
#define K3 (3 * D_MODEL)     /* 3072 */
#define NQT (SEQ / 64)       /* 32 q-tiles of 64 */
#define SCALE_Q 0.1803368867f /* 0.125 * log2(e): QK scores land in exp2 domain */

typedef unsigned short u16;
typedef unsigned int u32;
typedef __attribute__((ext_vector_type(8))) short short8;
typedef __attribute__((ext_vector_type(4))) float floatx4;

typedef const __attribute__((address_space(1))) u32* gptr_t;
typedef __attribute__((address_space(3))) u32* lptr_t;

// Packed f32x2 -> bf16x2 (RNE) in ONE instruction (m240-verified mnemonic).
__device__ __forceinline__ unsigned cvt_pk(float lo, float hi) {
    unsigned r;
    asm("v_cvt_pk_bf16_f32 %0, %1, %2" : "=v"(r) : "v"(lo), "v"(hi));
    return r;
}

// ------------------------------------------------------------ fused prep
// One kernel replaces conv + 2x weight transpose (saves 2 launch gaps).
__global__ __launch_bounds__(256) void prep_fused(const float* __restrict__ x,
                                                  u16* __restrict__ xb,
                                                  const float* __restrict__ w_qkv,
                                                  u16* __restrict__ wt_qkv,
                                                  const float* __restrict__ w_proj,
                                                  u16* __restrict__ wt_proj) {
    __shared__ u16 tile[64][65];
    const int bid = blockIdx.x;
    if (bid < 8192) {
        const int i = bid * 256 + threadIdx.x;
        float4 v = ((const float4*)x)[i];
        uint2 p;
        p.x = cvt_pk(v.x, v.y);
        p.y = cvt_pk(v.z, v.w);
        ((uint2*)xb)[i] = p;
        return;
    }
    const float* w;
    u16* wt;
    int C, bx, by;
    if (bid < 8192 + 768) {
        const int r = bid - 8192;
        w = w_qkv; wt = wt_qkv; C = K3;
        bx = r % 48; by = r / 48;
    } else {
        const int r = bid - 8960;
        w = w_proj; wt = wt_proj; C = D_MODEL;
        bx = r & 15; by = r >> 4;
    }
    const int R = D_MODEL;
    const int tx = threadIdx.x & 63;
    const int ty = threadIdx.x >> 6;
    const int r0 = by * 64, c0 = bx * 64;
    #pragma unroll
    for (int i = 0; i < 16; i += 2) {
        const float a = w[(size_t)(r0 + i * 4 + ty) * C + c0 + tx];
        const float b = w[(size_t)(r0 + (i + 1) * 4 + ty) * C + c0 + tx];
        const unsigned p = cvt_pk(a, b);
        tile[i * 4 + ty][tx] = (u16)p;
        tile[(i + 1) * 4 + ty][tx] = (u16)(p >> 16);
    }
    __syncthreads();
    #pragma unroll
    for (int i = 0; i < 16; ++i) {
        const int c = i * 4 + ty;
        wt[(size_t)(c0 + c) * R + r0 + tx] = tile[tx][c];
    }
}

// LDS-tiled: vt[bh][d][t] <- v[bh][t][d]; both sides coalesced. (R3-proven.)
__global__ __launch_bounds__(256) void transpose_v2(const u16* __restrict__ v,
                                                    u16* __restrict__ vt) {
    __shared__ u16 tile[64][65];
    const int bh = blockIdx.y;
    const int t0 = blockIdx.x * 64;
    const int tx = threadIdx.x & 63, ty = threadIdx.x >> 6;
    const u16* src = v + ((size_t)bh * SEQ + t0) * HEAD_DIM;
    #pragma unroll
    for (int i = 0; i < 16; ++i) {
        const int r = i * 4 + ty;
        tile[r][tx] = src[r * HEAD_DIM + tx];
    }
    __syncthreads();
    u16* dst = vt + (size_t)bh * HEAD_DIM * SEQ + t0;
    #pragma unroll
    for (int i = 0; i < 16; ++i) {
        const int d = i * 4 + ty;
        dst[(size_t)d * SEQ + tx] = tile[tx][d];
    }
}

// --------------------------------------------- pipelined QKV GEMM (T3+T4)
// 128x128 tile, BK=64, DOUBLE-BUFFERED LDS (64KB). Each K-step: issue next
// tile's 8 global_load_lds, then s_waitcnt vmcnt(8) (current tile's 8 loads
// retired; next tile's stay IN FLIGHT across the barrier), raw s_barrier,
// compute, s_barrier. Never drains vmcnt to 0 in the loop -> the ~600cy
// HBM/L2 latency that __syncthreads exposed 16x per block now hides under
// MFMA. Manually x2-unrolled so buffer indices are compile-time.
__global__ __launch_bounds__(256) void gemm_qkv(const u16* __restrict__ A,
                                                const u16* __restrict__ Bt,
                                                u16* __restrict__ qo,
                                                u16* __restrict__ ko,
                                                u16* __restrict__ vo) {
    __shared__ u16 As[2][128][64];
    __shared__ u16 Bs[2][128][64];
    const int tid  = threadIdx.x;
    const int wave = tid >> 6, lane = tid & 63;
    const int quad = lane >> 4, l15 = lane & 15;
    const int wr = wave >> 1, wc = wave & 1;
    const int bid = (int)(blockIdx.y * gridDim.x + blockIdx.x);
    const int nwg = (int)(gridDim.x * gridDim.y);
    const int swz = (bid & 7) * (nwg >> 3) + (bid >> 3);   /* XCD swizzle */
    const int m0 = (swz / 24) * 128, n0 = (swz % 24) * 128;
    const int lrow8 = lane >> 3;
    const int csw = 8 * ((lane & 7) ^ lrow8);      /* load-side swizzle */
    const int swA = (l15 & 7) * 8;                 /* read-side xor     */
    floatx4 acc[4][4] = {};
    const u16* Ab = A  + (size_t)m0 * D_MODEL + csw;
    const u16* Bb = Bt + (size_t)n0 * D_MODEL + csw;

#define QKV_ISSUE8(buf, k0)                                                    \
    _Pragma("unroll")                                                          \
    for (int i = 0; i < 4; ++i) {                                              \
        const int rb = i * 32 + wave * 8;                                      \
        __builtin_amdgcn_global_load_lds(                                      \
            (gptr_t)(Ab + (size_t)(rb + lrow8) * D_MODEL + (k0)),              \
            (lptr_t)(&As[buf][rb][0]), 16, 0, 0);                              \
        __builtin_amdgcn_global_load_lds(                                      \
            (gptr_t)(Bb + (size_t)(rb + lrow8) * D_MODEL + (k0)),              \
            (lptr_t)(&Bs[buf][rb][0]), 16, 0, 0);                              \
    }

#define QKV_COMPUTE(buf)                                                       \
    _Pragma("unroll")                                                          \
    for (int ks = 0; ks < 2; ++ks) {                                           \
        const int kk = ks * 32 + quad * 8;                                     \
        short8 af[4], bf[4];                                                   \
        _Pragma("unroll")                                                      \
        for (int t2 = 0; t2 < 4; ++t2) {                                       \
            af[t2] = *(const short8*)&As[buf][wr * 64 + t2 * 16 + l15][kk ^ swA]; \
            bf[t2] = *(const short8*)&Bs[buf][wc * 64 + t2 * 16 + l15][kk ^ swA]; \
        }                                                                      \
        _Pragma("unroll")                                                      \
        for (int i = 0; i < 4; ++i)                                            \
            _Pragma("unroll")                                                  \
            for (int j = 0; j < 4; ++j)                                        \
                acc[i][j] = __builtin_amdgcn_mfma_f32_16x16x32_bf16(           \
                    af[i], bf[j], acc[i][j], 0, 0, 0);                         \
    }

#define WAITV8 do { asm volatile("s_waitcnt vmcnt(8)" ::: "memory");           \
                    __builtin_amdgcn_sched_barrier(0); } while (0)
#define WAITV0 do { asm volatile("s_waitcnt vmcnt(0)" ::: "memory");           \
                    __builtin_amdgcn_sched_barrier(0); } while (0)
#define BARR   do { __builtin_amdgcn_s_barrier();                              \
                    __builtin_amdgcn_sched_barrier(0); } while (0)

    QKV_ISSUE8(0, 0)
    #pragma unroll 1
    for (int t = 0; t < 14; t += 2) {
        QKV_ISSUE8(1, (t + 1) * 64)
        WAITV8; BARR;
        QKV_COMPUTE(0)
        BARR;
        QKV_ISSUE8(0, (t + 2) * 64)
        WAITV8; BARR;
        QKV_COMPUTE(1)
        BARR;
    }
    QKV_ISSUE8(1, 15 * 64)
    WAITV8; BARR;
    QKV_COMPUTE(0)
    BARR;
    WAITV0; BARR;
    QKV_COMPUTE(1)

    // ---- epilogue (R3-proven): q (pre-scaled) / k / v all as [BH][T][64]
    const int which = n0 >> 10;                 // block-uniform
    u16* dst = which == 0 ? qo : (which == 1 ? ko : vo);
    const float scl = which == 0 ? SCALE_Q : 1.f;
    #pragma unroll
    for (int i = 0; i < 4; ++i)
        #pragma unroll
        for (int j = 0; j < 4; ++j) {
            const int col = n0 + wc * 64 + j * 16 + l15;
            const int rb  = m0 + wr * 64 + i * 16 + quad * 4;
            const int cc  = col & 1023;
            const int h = cc >> 6, d = cc & 63;
            #pragma unroll
            for (int rr = 0; rr < 4; rr += 2) {
                const unsigned pw = cvt_pk(acc[i][j][rr] * scl,
                                           acc[i][j][rr + 1] * scl);
                int row = rb + rr;
                int b_ = row >> 11, t_ = row & 2047;
                dst[(((size_t)(b_ * N_HEADS + h)) * SEQ + t_) * HEAD_DIM + d] =
                    (u16)pw;
                row = rb + rr + 1;
                b_ = row >> 11; t_ = row & 2047;
                dst[(((size_t)(b_ * N_HEADS + h)) * SEQ + t_) * HEAD_DIM + d] =
                    (u16)(pw >> 16);
            }
        }
}

// ---------------------------------------------------------------- GEMM core
// (R3-proven m97 structure, static LDS arrays) — used by gemm_proj only.
#define GEMM_CORE_GLD(KDIM, NXB)                                               \
    __shared__ u16 As[128][64];                                                \
    __shared__ u16 Bs[128][64];                                                \
    const int tid  = threadIdx.x;                                              \
    const int wave = tid >> 6, lane = tid & 63;                                \
    const int quad = lane >> 4, l15 = lane & 15;                               \
    const int wr = wave >> 1, wc = wave & 1;                                   \
    const int bid = (int)(blockIdx.y * gridDim.x + blockIdx.x);                \
    const int nwg = (int)(gridDim.x * gridDim.y);                              \
    const int swz = (bid & 7) * (nwg >> 3) + (bid >> 3);   /* XCD swizzle */   \
    const int m0 = (swz / (NXB)) * 128, n0 = (swz % (NXB)) * 128;              \
    const int lrow8 = lane >> 3;                                               \
    const int csw = 8 * ((lane & 7) ^ lrow8);      /* load-side swizzle */     \
    const int swA = (l15 & 7) * 8;                 /* read-side xor     */     \
    floatx4 acc[4][4] = {};                                                    \
    for (int k0 = 0; k0 < (KDIM); k0 += 64) {                                  \
        _Pragma("unroll")                                                      \
        for (int i = 0; i < 4; ++i) {                                          \
            const int rb = i * 32 + wave * 8;                                  \
            const int r  = rb + lrow8;                                         \
            __builtin_amdgcn_global_load_lds(                                  \
                (gptr_t)(A + (size_t)(m0 + r) * (KDIM) + k0 + csw),            \
                (lptr_t)(&As[rb][0]), 16, 0, 0);                               \
            __builtin_amdgcn_global_load_lds(                                  \
                (gptr_t)(Bt + (size_t)(n0 + r) * (KDIM) + k0 + csw),           \
                (lptr_t)(&Bs[rb][0]), 16, 0, 0);                               \
        }                                                                      \
        __syncthreads();                                                       \
        _Pragma("unroll")                                                      \
        for (int ks = 0; ks < 2; ++ks) {                                       \
            const int kk = ks * 32 + quad * 8;                                 \
            short8 af[4], bf[4];                                               \
            _Pragma("unroll")                                                  \
            for (int t = 0; t < 4; ++t) {                                      \
                af[t] = *(const short8*)&As[wr * 64 + t * 16 + l15][kk ^ swA]; \
                bf[t] = *(const short8*)&Bs[wc * 64 + t * 16 + l15][kk ^ swA]; \
            }                                                                  \
            _Pragma("unroll")                                                  \
            for (int i = 0; i < 4; ++i)                                        \
                _Pragma("unroll")                                              \
                for (int j = 0; j < 4; ++j)                                    \
                    acc[i][j] = __builtin_amdgcn_mfma_f32_16x16x32_bf16(       \
                        af[i], bf[j], acc[i][j], 0, 0, 0);                     \
        }                                                                      \
        __syncthreads();                                                       \
    }

// GEMM2: attn_out[8192][1024] @ wproj + bias -> d_out fp32
__global__ __launch_bounds__(256) void gemm_proj(const u16* __restrict__ A,
                                                 const u16* __restrict__ Bt,
                                                 const float* __restrict__ bias,
                                                 float* __restrict__ out) {
    GEMM_CORE_GLD(D_MODEL, 8)
    #pragma unroll
    for (int i = 0; i < 4; ++i)
        #pragma unroll
        for (int j = 0; j < 4; ++j) {
            const int col = n0 + wc * 64 + j * 16 + l15;
            const int rb  = m0 + wr * 64 + i * 16 + quad * 4;
            const float bv = bias[col];
            #pragma unroll
            for (int rr = 0; rr < 4; ++rr) {
                const int row = rb + rr;
                out[(size_t)row * D_MODEL + col] = acc[i][j][rr] + bv;
            }
        }
}

// ------------------------------------------------------- MFMA flash attention
// R3-proven structure (74.6us) + T5 setprio. K=32 MFMAs, Plds round-trip,
// double-buffered K/V staging, one barrier per chunk, XCD-swizzled blocks.
__global__ __launch_bounds__(256, 4) void attn_mfma(const u16* __restrict__ q,
                                                    const u16* __restrict__ k,
                                                    const u16* __restrict__ vt,
                                                    u16* __restrict__ o) {
    __shared__ u16 Ks[2][64][64];
    __shared__ u16 Vs[2][64][64];
    __shared__ u16 Plds[4][16][64];
    const int tid = threadIdx.x;
    const int w = tid >> 6, lane = tid & 63;
    const int quad = lane >> 4, l15 = lane & 15;
    const int bid = (int)(blockIdx.y * 16 + blockIdx.x);
    const int swzb = (bid & 7) * 128 + (bid >> 3);
    const int bh = swzb >> 4;
    const int qx = swzb & 15;
    const int b = bh >> 4, h = bh & 15;
    const u16* kb  = k  + (size_t)bh * SEQ * HEAD_DIM;
    const u16* vtb = vt + (size_t)bh * HEAD_DIM * SEQ;
    const int lrow8 = lane >> 3;                   // 0..7
    const int csw = 8 * ((lane & 7) ^ lrow8);      // load-side swizzle
    const int swA = (l15 & 7) * 8;                 // read-side xor
    const int r0 = w * 16 + lrow8;                 // staging row
    const short8 ones = {0x3F80, 0x3F80, 0x3F80, 0x3F80,
                         0x3F80, 0x3F80, 0x3F80, 0x3F80}; // bf16 1.0 x8

    #pragma unroll 1
    for (int seg = 0; seg < 2; ++seg) {
        const int qt = seg ? qx : (NQT - 1 - qx);
        const int qrow = qt * 64 + w * 16 + l15;
        const u16* qp = q + ((size_t)bh * SEQ + qrow) * HEAD_DIM + quad * 8;
        const short8 bq0 = *(const short8*)(qp);
        const short8 bq1 = *(const short8*)(qp + 32);

        floatx4 O[4] = {};
        floatx4 Lacc = {};

        __syncthreads();   // prior segment's buffer reads complete
        // stage chunk 0 -> buffer 0
        __builtin_amdgcn_global_load_lds(
            (gptr_t)(kb + (size_t)(r0) * HEAD_DIM + csw),
            (lptr_t)(&Ks[0][w * 16][0]), 16, 0, 0);
        __builtin_amdgcn_global_load_lds(
            (gptr_t)(kb + (size_t)(r0 + 8) * HEAD_DIM + csw),
            (lptr_t)(&Ks[0][w * 16 + 8][0]), 16, 0, 0);
        __builtin_amdgcn_global_load_lds(
            (gptr_t)(vtb + (size_t)(r0) * SEQ + csw),
            (lptr_t)(&Vs[0][w * 16][0]), 16, 0, 0);
        __builtin_amdgcn_global_load_lds(
            (gptr_t)(vtb + (size_t)(r0 + 8) * SEQ + csw),
            (lptr_t)(&Vs[0][w * 16 + 8][0]), 16, 0, 0);

        for (int c = 0; c <= qt; ++c) {
            const int cb = c & 1;
            __syncthreads();   // staging(c) drained everywhere; buf[(c+1)&1] free
            if (c < qt) {
                const int nb = cb ^ 1;
                __builtin_amdgcn_global_load_lds(
                    (gptr_t)(kb + (size_t)((c + 1) * 64 + r0) * HEAD_DIM + csw),
                    (lptr_t)(&Ks[nb][w * 16][0]), 16, 0, 0);
                __builtin_amdgcn_global_load_lds(
                    (gptr_t)(kb + (size_t)((c + 1) * 64 + r0 + 8) * HEAD_DIM + csw),
                    (lptr_t)(&Ks[nb][w * 16 + 8][0]), 16, 0, 0);
                __builtin_amdgcn_global_load_lds(
                    (gptr_t)(vtb + (size_t)(r0) * SEQ + (c + 1) * 64 + csw),
                    (lptr_t)(&Vs[nb][w * 16][0]), 16, 0, 0);
                __builtin_amdgcn_global_load_lds(
                    (gptr_t)(vtb + (size_t)(r0 + 8) * SEQ + (c + 1) * 64 + csw),
                    (lptr_t)(&Vs[nb][w * 16 + 8][0]), 16, 0, 0);
            }
            // ---- QK^T from LDS buf cb
            floatx4 s[4];
            #pragma unroll
            for (int kt = 0; kt < 4; ++kt) {
                short8 ak0 = *(const short8*)&Ks[cb][kt * 16 + l15][(quad * 8) ^ swA];
                short8 ak1 = *(const short8*)&Ks[cb][kt * 16 + l15][(32 + quad * 8) ^ swA];
                floatx4 z = {};
                __builtin_amdgcn_s_setprio(1);
                z = __builtin_amdgcn_mfma_f32_16x16x32_bf16(ak0, bq0, z, 0, 0, 0);
                z = __builtin_amdgcn_mfma_f32_16x16x32_bf16(ak1, bq1, z, 0, 0, 0);
                __builtin_amdgcn_s_setprio(0);
                s[kt] = z;
            }
            // ---- exp2 (m=0) + diagonal mask
            float e[4][4];
            #pragma unroll
            for (int kt = 0; kt < 4; ++kt)
                #pragma unroll
                for (int r = 0; r < 4; ++r)
                    e[kt][r] = exp2f(s[kt][r]);
            if (c == qt) {
                #pragma unroll
                for (int kt = 0; kt < 4; ++kt)
                    #pragma unroll
                    for (int r = 0; r < 4; ++r)
                        if (kt * 16 + quad * 4 + r > w * 16 + l15) e[kt][r] = 0.f;
            }
            // ---- P->LDS (packed cvt_pk, swizzled cols)
            #pragma unroll
            for (int kt = 0; kt < 4; ++kt) {
                uint2 pkv;
                pkv.x = cvt_pk(e[kt][0], e[kt][1]);
                pkv.y = cvt_pk(e[kt][2], e[kt][3]);
                *(uint2*)&Plds[w][l15][(kt * 16 + quad * 4) ^ swA] = pkv;
            }
            // ---- PV from LDS: O^T += Vs . P^T ; l via ones-row MFMA over P
            short8 pb0 = *(const short8*)&Plds[w][l15][(quad * 8) ^ swA];
            short8 pb1 = *(const short8*)&Plds[w][l15][(32 + quad * 8) ^ swA];
            __builtin_amdgcn_s_setprio(1);
            #pragma unroll
            for (int dt = 0; dt < 4; ++dt) {
                short8 av0 = *(const short8*)&Vs[cb][dt * 16 + l15][(quad * 8) ^ swA];
                short8 av1 = *(const short8*)&Vs[cb][dt * 16 + l15][(32 + quad * 8) ^ swA];
                O[dt] = __builtin_amdgcn_mfma_f32_16x16x32_bf16(av0, pb0, O[dt], 0, 0, 0);
                O[dt] = __builtin_amdgcn_mfma_f32_16x16x32_bf16(av1, pb1, O[dt], 0, 0, 0);
            }
            Lacc = __builtin_amdgcn_mfma_f32_16x16x32_bf16(ones, pb0, Lacc, 0, 0, 0);
            Lacc = __builtin_amdgcn_mfma_f32_16x16x32_bf16(ones, pb1, Lacc, 0, 0, 0);
            __builtin_amdgcn_s_setprio(0);
        }
        // ---- epilogue: l is already the full-row sum in every Lacc reg
        const float inv = 1.f / Lacc[0];
        u16* op = o + ((size_t)(b * SEQ + qrow)) * D_MODEL + h * 64 + quad * 4;
        #pragma unroll
        for (int dt = 0; dt < 4; ++dt) {
            uint2 pkv;
            pkv.x = cvt_pk(O[dt][0] * inv, O[dt][1] * inv);
            pkv.y = cvt_pk(O[dt][2] * inv, O[dt][3] * inv);
            *(uint2*)(op + dt * 16) = pkv;
        }
    }
}

// ---------------------------------------------------------------- launch
extern "C" void kernel_launch(void* const* d_in, const int* in_sizes, int n_in,
                              void* d_out, int out_size, void* d_ws, size_t ws_size,
                              hipStream_t stream) {
    const float* x      = (const float*)d_in[0];
    const float* w_qkv  = (const float*)d_in[1];
    const float* w_proj = (const float*)d_in[2];
    const float* b_proj = (const float*)d_in[3];
    float* out = (float*)d_out;

    u16* xb      = (u16*)d_ws;                                 // [8192][1024]
    u16* wt_qkv  = xb + (size_t)ROWS * D_MODEL;                // [3072][1024]
    u16* wt_proj = wt_qkv + (size_t)D_MODEL * K3;              // [1024][1024]
    u16* qws     = wt_proj + (size_t)D_MODEL * D_MODEL;        // [BH][T][64] (pre-scaled)
    u16* kws     = qws + (size_t)ROWS * D_MODEL;               // [BH][T][64]
    u16* vtws    = kws + (size_t)ROWS * D_MODEL;               // [BH][64][T]
    u16* aout    = vtws + (size_t)ROWS * D_MODEL;              // [8192][1024]
    u16* vnat    = aout;   // V natural layout aliases aout (consumed by
                           // transpose_v2 before attn writes aout)

    prep_fused<<<8192 + 768 + 256, 256, 0, stream>>>(x, xb, w_qkv, wt_qkv,
                                                     w_proj, wt_proj);

    gemm_qkv<<<dim3(K3 / 128, ROWS / 128), 256, 0, stream>>>(xb, wt_qkv, qws, kws, vnat);

    transpose_v2<<<dim3(SEQ / 64, BATCH * N_HEADS), 256, 0, stream>>>(vnat, vtws);

    attn_mfma<<<dim3(NQT / 2, BATCH * N_HEADS), 256, 0, stream>>>(qws, kws, vtws, aout);

    gemm_proj<<<dim3(D_MODEL / 128, ROWS / 128), 256, 0, stream>>>(aout, wt_proj, b_proj, out);
}

// Round 7
// 241.355 us; speedup vs baseline: 1.0904x; 1.0435x over previous
//
#include <hip/hip_runtime.h>
#include <stdint.h>

#define D_MODEL 1024
#define N_HEADS 16
#define HEAD_DIM 64
#define BATCH 4
#define SEQ 2048
#define ROWS (BATCH * SEQ)   /* 8192 */
#define K3 (3 * D_MODEL)     /* 3072 */
#define NQT (SEQ / 64)       /* 32 q-tiles of 64 */
#define SCALE_Q 0.1803368867f /* 0.125 * log2(e): QK scores land in exp2 domain */

typedef unsigned short u16;
typedef unsigned int u32;
typedef __attribute__((ext_vector_type(8))) short short8;
typedef __attribute__((ext_vector_type(4))) float floatx4;

typedef const __attribute__((address_space(1))) u32* gptr_t;
typedef __attribute__((address_space(3))) u32* lptr_t;

// Packed f32x2 -> bf16x2 (RNE) in ONE instruction (m240-verified mnemonic).
__device__ __forceinline__ unsigned cvt_pk(float lo, float hi) {
    unsigned r;
    asm("v_cvt_pk_bf16_f32 %0, %1, %2" : "=v"(r) : "v"(lo), "v"(hi));
    return r;
}

// ------------------------------------------------------------ fused prep
// One kernel replaces conv + 2x weight transpose (saves 2 launch gaps).
__global__ __launch_bounds__(256) void prep_fused(const float* __restrict__ x,
                                                  u16* __restrict__ xb,
                                                  const float* __restrict__ w_qkv,
                                                  u16* __restrict__ wt_qkv,
                                                  const float* __restrict__ w_proj,
                                                  u16* __restrict__ wt_proj) {
    __shared__ u16 tile[64][65];
    const int bid = blockIdx.x;
    if (bid < 8192) {
        const int i = bid * 256 + threadIdx.x;
        float4 v = ((const float4*)x)[i];
        uint2 p;
        p.x = cvt_pk(v.x, v.y);
        p.y = cvt_pk(v.z, v.w);
        ((uint2*)xb)[i] = p;
        return;
    }
    const float* w;
    u16* wt;
    int C, bx, by;
    if (bid < 8192 + 768) {
        const int r = bid - 8192;
        w = w_qkv; wt = wt_qkv; C = K3;
        bx = r % 48; by = r / 48;
    } else {
        const int r = bid - 8960;
        w = w_proj; wt = wt_proj; C = D_MODEL;
        bx = r & 15; by = r >> 4;
    }
    const int R = D_MODEL;
    const int tx = threadIdx.x & 63;
    const int ty = threadIdx.x >> 6;
    const int r0 = by * 64, c0 = bx * 64;
    #pragma unroll
    for (int i = 0; i < 16; i += 2) {
        const float a = w[(size_t)(r0 + i * 4 + ty) * C + c0 + tx];
        const float b = w[(size_t)(r0 + (i + 1) * 4 + ty) * C + c0 + tx];
        const unsigned p = cvt_pk(a, b);
        tile[i * 4 + ty][tx] = (u16)p;
        tile[(i + 1) * 4 + ty][tx] = (u16)(p >> 16);
    }
    __syncthreads();
    #pragma unroll
    for (int i = 0; i < 16; ++i) {
        const int c = i * 4 + ty;
        wt[(size_t)(c0 + c) * R + r0 + tx] = tile[tx][c];
    }
}

// LDS-tiled: vt[bh][d][t] <- v[bh][t][d]; both sides coalesced. (R3-proven.)
__global__ __launch_bounds__(256) void transpose_v2(const u16* __restrict__ v,
                                                    u16* __restrict__ vt) {
    __shared__ u16 tile[64][65];
    const int bh = blockIdx.y;
    const int t0 = blockIdx.x * 64;
    const int tx = threadIdx.x & 63, ty = threadIdx.x >> 6;
    const u16* src = v + ((size_t)bh * SEQ + t0) * HEAD_DIM;
    #pragma unroll
    for (int i = 0; i < 16; ++i) {
        const int r = i * 4 + ty;
        tile[r][tx] = src[r * HEAD_DIM + tx];
    }
    __syncthreads();
    u16* dst = vt + (size_t)bh * HEAD_DIM * SEQ + t0;
    #pragma unroll
    for (int i = 0; i < 16; ++i) {
        const int d = i * 4 + ty;
        dst[(size_t)d * SEQ + tx] = tile[tx][d];
    }
}

// --------------------------------------------- pipelined GEMM core (T3+T4)
// 128x128 tile, BK=64, DOUBLE-BUFFERED LDS (64KB). Each K-step: issue next
// tile's 8 global_load_lds, s_waitcnt vmcnt(8) (current tile retired; next
// tile's loads stay IN FLIGHT across the barrier), s_barrier, compute,
// s_barrier. Never drains vmcnt to 0 in the loop. Validated on gemm_qkv in
// R6 (dropped out of top-5; was 84.7us in R5). K fixed at 1024 (16 tiles).
#define PIPE_ISSUE8(buf, k0)                                                   \
    _Pragma("unroll")                                                          \
    for (int i = 0; i < 4; ++i) {                                              \
        const int rb = i * 32 + wave * 8;                                      \
        __builtin_amdgcn_global_load_lds(                                      \
            (gptr_t)(Ab + (size_t)(rb + lrow8) * D_MODEL + (k0)),              \
            (lptr_t)(&As[buf][rb][0]), 16, 0, 0);                              \
        __builtin_amdgcn_global_load_lds(                                      \
            (gptr_t)(Bb + (size_t)(rb + lrow8) * D_MODEL + (k0)),              \
            (lptr_t)(&Bs[buf][rb][0]), 16, 0, 0);                              \
    }

#define PIPE_COMPUTE(buf)                                                      \
    _Pragma("unroll")                                                          \
    for (int ks = 0; ks < 2; ++ks) {                                           \
        const int kk = ks * 32 + quad * 8;                                     \
        short8 af[4], bf[4];                                                   \
        _Pragma("unroll")                                                      \
        for (int t2 = 0; t2 < 4; ++t2) {                                       \
            af[t2] = *(const short8*)&As[buf][wr * 64 + t2 * 16 + l15][kk ^ swA]; \
            bf[t2] = *(const short8*)&Bs[buf][wc * 64 + t2 * 16 + l15][kk ^ swA]; \
        }                                                                      \
        _Pragma("unroll")                                                      \
        for (int i = 0; i < 4; ++i)                                            \
            _Pragma("unroll")                                                  \
            for (int j = 0; j < 4; ++j)                                        \
                acc[i][j] = __builtin_amdgcn_mfma_f32_16x16x32_bf16(           \
                    af[i], bf[j], acc[i][j], 0, 0, 0);                         \
    }

#define WAITV8 do { asm volatile("s_waitcnt vmcnt(8)" ::: "memory");           \
                    __builtin_amdgcn_sched_barrier(0); } while (0)
#define WAITV0 do { asm volatile("s_waitcnt vmcnt(0)" ::: "memory");           \
                    __builtin_amdgcn_sched_barrier(0); } while (0)
#define BARR   do { __builtin_amdgcn_s_barrier();                              \
                    __builtin_amdgcn_sched_barrier(0); } while (0)

#define GEMM_PIPE(NXB)                                                         \
    __shared__ u16 As[2][128][64];                                             \
    __shared__ u16 Bs[2][128][64];                                             \
    const int tid  = threadIdx.x;                                              \
    const int wave = tid >> 6, lane = tid & 63;                                \
    const int quad = lane >> 4, l15 = lane & 15;                               \
    const int wr = wave >> 1, wc = wave & 1;                                   \
    const int bid = (int)(blockIdx.y * gridDim.x + blockIdx.x);                \
    const int nwg = (int)(gridDim.x * gridDim.y);                              \
    const int swz = (bid & 7) * (nwg >> 3) + (bid >> 3);   /* XCD swizzle */   \
    const int m0 = (swz / (NXB)) * 128, n0 = (swz % (NXB)) * 128;              \
    const int lrow8 = lane >> 3;                                               \
    const int csw = 8 * ((lane & 7) ^ lrow8);      /* load-side swizzle */     \
    const int swA = (l15 & 7) * 8;                 /* read-side xor     */     \
    floatx4 acc[4][4] = {};                                                    \
    const u16* Ab = A  + (size_t)m0 * D_MODEL + csw;                           \
    const u16* Bb = Bt + (size_t)n0 * D_MODEL + csw;                           \
    PIPE_ISSUE8(0, 0)                                                          \
    _Pragma("unroll 1")                                                        \
    for (int t = 0; t < 14; t += 2) {                                          \
        PIPE_ISSUE8(1, (t + 1) * 64)                                           \
        WAITV8; BARR;                                                          \
        PIPE_COMPUTE(0)                                                        \
        BARR;                                                                  \
        PIPE_ISSUE8(0, (t + 2) * 64)                                           \
        WAITV8; BARR;                                                          \
        PIPE_COMPUTE(1)                                                        \
        BARR;                                                                  \
    }                                                                          \
    PIPE_ISSUE8(1, 15 * 64)                                                    \
    WAITV8; BARR;                                                              \
    PIPE_COMPUTE(0)                                                            \
    BARR;                                                                      \
    WAITV0; BARR;                                                              \
    PIPE_COMPUTE(1)

// GEMM1: xb @ wqkv -> q (pre-scaled), k, v ALL as [BH][T][64]
__global__ __launch_bounds__(256) void gemm_qkv(const u16* __restrict__ A,
                                                const u16* __restrict__ Bt,
                                                u16* __restrict__ qo,
                                                u16* __restrict__ ko,
                                                u16* __restrict__ vo) {
    GEMM_PIPE(24)
    const int which = n0 >> 10;                 // block-uniform
    u16* dst = which == 0 ? qo : (which == 1 ? ko : vo);
    const float scl = which == 0 ? SCALE_Q : 1.f;
    #pragma unroll
    for (int i = 0; i < 4; ++i)
        #pragma unroll
        for (int j = 0; j < 4; ++j) {
            const int col = n0 + wc * 64 + j * 16 + l15;
            const int rb  = m0 + wr * 64 + i * 16 + quad * 4;
            const int cc  = col & 1023;
            const int h = cc >> 6, d = cc & 63;
            #pragma unroll
            for (int rr = 0; rr < 4; rr += 2) {
                const unsigned pw = cvt_pk(acc[i][j][rr] * scl,
                                           acc[i][j][rr + 1] * scl);
                int row = rb + rr;
                int b_ = row >> 11, t_ = row & 2047;
                dst[(((size_t)(b_ * N_HEADS + h)) * SEQ + t_) * HEAD_DIM + d] =
                    (u16)pw;
                row = rb + rr + 1;
                b_ = row >> 11; t_ = row & 2047;
                dst[(((size_t)(b_ * N_HEADS + h)) * SEQ + t_) * HEAD_DIM + d] =
                    (u16)(pw >> 16);
            }
        }
}

// GEMM2: attn_out[8192][1024] @ wproj + bias -> d_out fp32 (now pipelined too)
__global__ __launch_bounds__(256) void gemm_proj(const u16* __restrict__ A,
                                                 const u16* __restrict__ Bt,
                                                 const float* __restrict__ bias,
                                                 float* __restrict__ out) {
    GEMM_PIPE(8)
    #pragma unroll
    for (int i = 0; i < 4; ++i)
        #pragma unroll
        for (int j = 0; j < 4; ++j) {
            const int col = n0 + wc * 64 + j * 16 + l15;
            const int rb  = m0 + wr * 64 + i * 16 + quad * 4;
            const float bv = bias[col];
            #pragma unroll
            for (int rr = 0; rr < 4; ++rr) {
                const int row = rb + rr;
                out[(size_t)row * D_MODEL + col] = acc[i][j][rr] + bv;
            }
        }
}

// ------------------------------------------------------- MFMA flash attention
// EXACT R3 structure (measured 74.6us; best). setprio REMOVED: R6 measured it
// at 76.2-76.6us -- our 4-wave barrier-lockstep block is the m190 regime where
// setprio is null-to-negative, not the m191 independent-wave regime.
__global__ __launch_bounds__(256, 4) void attn_mfma(const u16* __restrict__ q,
                                                    const u16* __restrict__ k,
                                                    const u16* __restrict__ vt,
                                                    u16* __restrict__ o) {
    __shared__ u16 Ks[2][64][64];
    __shared__ u16 Vs[2][64][64];
    __shared__ u16 Plds[4][16][64];
    const int tid = threadIdx.x;
    const int w = tid >> 6, lane = tid & 63;
    const int quad = lane >> 4, l15 = lane & 15;
    const int bid = (int)(blockIdx.y * 16 + blockIdx.x);
    const int swzb = (bid & 7) * 128 + (bid >> 3);
    const int bh = swzb >> 4;
    const int qx = swzb & 15;
    const int b = bh >> 4, h = bh & 15;
    const u16* kb  = k  + (size_t)bh * SEQ * HEAD_DIM;
    const u16* vtb = vt + (size_t)bh * HEAD_DIM * SEQ;
    const int lrow8 = lane >> 3;                   // 0..7
    const int csw = 8 * ((lane & 7) ^ lrow8);      // load-side swizzle
    const int swA = (l15 & 7) * 8;                 // read-side xor
    const int r0 = w * 16 + lrow8;                 // staging row
    const short8 ones = {0x3F80, 0x3F80, 0x3F80, 0x3F80,
                         0x3F80, 0x3F80, 0x3F80, 0x3F80}; // bf16 1.0 x8

    #pragma unroll 1
    for (int seg = 0; seg < 2; ++seg) {
        const int qt = seg ? qx : (NQT - 1 - qx);
        const int qrow = qt * 64 + w * 16 + l15;
        const u16* qp = q + ((size_t)bh * SEQ + qrow) * HEAD_DIM + quad * 8;
        const short8 bq0 = *(const short8*)(qp);
        const short8 bq1 = *(const short8*)(qp + 32);

        floatx4 O[4] = {};
        floatx4 Lacc = {};

        __syncthreads();   // prior segment's buffer reads complete
        // stage chunk 0 -> buffer 0
        __builtin_amdgcn_global_load_lds(
            (gptr_t)(kb + (size_t)(r0) * HEAD_DIM + csw),
            (lptr_t)(&Ks[0][w * 16][0]), 16, 0, 0);
        __builtin_amdgcn_global_load_lds(
            (gptr_t)(kb + (size_t)(r0 + 8) * HEAD_DIM + csw),
            (lptr_t)(&Ks[0][w * 16 + 8][0]), 16, 0, 0);
        __builtin_amdgcn_global_load_lds(
            (gptr_t)(vtb + (size_t)(r0) * SEQ + csw),
            (lptr_t)(&Vs[0][w * 16][0]), 16, 0, 0);
        __builtin_amdgcn_global_load_lds(
            (gptr_t)(vtb + (size_t)(r0 + 8) * SEQ + csw),
            (lptr_t)(&Vs[0][w * 16 + 8][0]), 16, 0, 0);

        for (int c = 0; c <= qt; ++c) {
            const int cb = c & 1;
            __syncthreads();   // staging(c) drained everywhere; buf[(c+1)&1] free
            if (c < qt) {
                const int nb = cb ^ 1;
                __builtin_amdgcn_global_load_lds(
                    (gptr_t)(kb + (size_t)((c + 1) * 64 + r0) * HEAD_DIM + csw),
                    (lptr_t)(&Ks[nb][w * 16][0]), 16, 0, 0);
                __builtin_amdgcn_global_load_lds(
                    (gptr_t)(kb + (size_t)((c + 1) * 64 + r0 + 8) * HEAD_DIM + csw),
                    (lptr_t)(&Ks[nb][w * 16 + 8][0]), 16, 0, 0);
                __builtin_amdgcn_global_load_lds(
                    (gptr_t)(vtb + (size_t)(r0) * SEQ + (c + 1) * 64 + csw),
                    (lptr_t)(&Vs[nb][w * 16][0]), 16, 0, 0);
                __builtin_amdgcn_global_load_lds(
                    (gptr_t)(vtb + (size_t)(r0 + 8) * SEQ + (c + 1) * 64 + csw),
                    (lptr_t)(&Vs[nb][w * 16 + 8][0]), 16, 0, 0);
            }
            // ---- QK^T from LDS buf cb
            floatx4 s[4];
            #pragma unroll
            for (int kt = 0; kt < 4; ++kt) {
                short8 ak0 = *(const short8*)&Ks[cb][kt * 16 + l15][(quad * 8) ^ swA];
                short8 ak1 = *(const short8*)&Ks[cb][kt * 16 + l15][(32 + quad * 8) ^ swA];
                floatx4 z = {};
                z = __builtin_amdgcn_mfma_f32_16x16x32_bf16(ak0, bq0, z, 0, 0, 0);
                z = __builtin_amdgcn_mfma_f32_16x16x32_bf16(ak1, bq1, z, 0, 0, 0);
                s[kt] = z;
            }
            // ---- exp2 (m=0) + diagonal mask
            float e[4][4];
            #pragma unroll
            for (int kt = 0; kt < 4; ++kt)
                #pragma unroll
                for (int r = 0; r < 4; ++r)
                    e[kt][r] = exp2f(s[kt][r]);
            if (c == qt) {
                #pragma unroll
                for (int kt = 0; kt < 4; ++kt)
                    #pragma unroll
                    for (int r = 0; r < 4; ++r)
                        if (kt * 16 + quad * 4 + r > w * 16 + l15) e[kt][r] = 0.f;
            }
            // ---- P->LDS (packed cvt_pk, swizzled cols)
            #pragma unroll
            for (int kt = 0; kt < 4; ++kt) {
                uint2 pkv;
                pkv.x = cvt_pk(e[kt][0], e[kt][1]);
                pkv.y = cvt_pk(e[kt][2], e[kt][3]);
                *(uint2*)&Plds[w][l15][(kt * 16 + quad * 4) ^ swA] = pkv;
            }
            // ---- PV from LDS: O^T += Vs . P^T ; l via ones-row MFMA over P
            short8 pb0 = *(const short8*)&Plds[w][l15][(quad * 8) ^ swA];
            short8 pb1 = *(const short8*)&Plds[w][l15][(32 + quad * 8) ^ swA];
            #pragma unroll
            for (int dt = 0; dt < 4; ++dt) {
                short8 av0 = *(const short8*)&Vs[cb][dt * 16 + l15][(quad * 8) ^ swA];
                short8 av1 = *(const short8*)&Vs[cb][dt * 16 + l15][(32 + quad * 8) ^ swA];
                O[dt] = __builtin_amdgcn_mfma_f32_16x16x32_bf16(av0, pb0, O[dt], 0, 0, 0);
                O[dt] = __builtin_amdgcn_mfma_f32_16x16x32_bf16(av1, pb1, O[dt], 0, 0, 0);
            }
            Lacc = __builtin_amdgcn_mfma_f32_16x16x32_bf16(ones, pb0, Lacc, 0, 0, 0);
            Lacc = __builtin_amdgcn_mfma_f32_16x16x32_bf16(ones, pb1, Lacc, 0, 0, 0);
        }
        // ---- epilogue: l is already the full-row sum in every Lacc reg
        const float inv = 1.f / Lacc[0];
        u16* op = o + ((size_t)(b * SEQ + qrow)) * D_MODEL + h * 64 + quad * 4;
        #pragma unroll
        for (int dt = 0; dt < 4; ++dt) {
            uint2 pkv;
            pkv.x = cvt_pk(O[dt][0] * inv, O[dt][1] * inv);
            pkv.y = cvt_pk(O[dt][2] * inv, O[dt][3] * inv);
            *(uint2*)(op + dt * 16) = pkv;
        }
    }
}

// ---------------------------------------------------------------- launch
extern "C" void kernel_launch(void* const* d_in, const int* in_sizes, int n_in,
                              void* d_out, int out_size, void* d_ws, size_t ws_size,
                              hipStream_t stream) {
    const float* x      = (const float*)d_in[0];
    const float* w_qkv  = (const float*)d_in[1];
    const float* w_proj = (const float*)d_in[2];
    const float* b_proj = (const float*)d_in[3];
    float* out = (float*)d_out;

    u16* xb      = (u16*)d_ws;                                 // [8192][1024]
    u16* wt_qkv  = xb + (size_t)ROWS * D_MODEL;                // [3072][1024]
    u16* wt_proj = wt_qkv + (size_t)D_MODEL * K3;              // [1024][1024]
    u16* qws     = wt_proj + (size_t)D_MODEL * D_MODEL;        // [BH][T][64] (pre-scaled)
    u16* kws     = qws + (size_t)ROWS * D_MODEL;               // [BH][T][64]
    u16* vtws    = kws + (size_t)ROWS * D_MODEL;               // [BH][64][T]
    u16* aout    = vtws + (size_t)ROWS * D_MODEL;              // [8192][1024]
    u16* vnat    = aout;   // V natural layout aliases aout (consumed by
                           // transpose_v2 before attn writes aout)

    prep_fused<<<8192 + 768 + 256, 256, 0, stream>>>(x, xb, w_qkv, wt_qkv,
                                                     w_proj, wt_proj);

    gemm_qkv<<<dim3(K3 / 128, ROWS / 128), 256, 0, stream>>>(xb, wt_qkv, qws, kws, vnat);

    transpose_v2<<<dim3(SEQ / 64, BATCH * N_HEADS), 256, 0, stream>>>(vnat, vtws);

    attn_mfma<<<dim3(NQT / 2, BATCH * N_HEADS), 256, 0, stream>>>(qws, kws, vtws, aout);

    gemm_proj<<<dim3(D_MODEL / 128, ROWS / 128), 256, 0, stream>>>(aout, wt_proj, b_proj, out);
}